// Round 19
// baseline (912.070 us; speedup 1.0000x reference)
//
#include <hip/hip_runtime.h>

// ===========================================================================
// Compile-time construction of the e3nn real Wigner-3j path tensor.
// (numerically validated rounds 3-18: absmax 0.031 vs threshold 0.259)
// ===========================================================================
namespace cg {

constexpr double csqrt(double x) {
    double g = x < 1.0 ? 1.0 : x;
    for (int i = 0; i < 64; ++i) g = 0.5 * (g + x / g);
    return g;
}
constexpr double fact(int n) { double r = 1.0; for (int i = 2; i <= n; ++i) r *= (double)i; return r; }

constexpr double su2cg(int j1, int j2, int j3, int m1, int m2, int m3) {
    if (m1 + m2 != m3) return 0.0;
    double pre = csqrt((2.0*j3+1.0)*fact(j3+j1-j2)*fact(j3-j1+j2)*fact(j1+j2-j3)
                       *fact(j3+m3)*fact(j3-m3)
                       /(fact(j1+j2+j3+1)*fact(j1-m1)*fact(j1+m1)*fact(j2-m2)*fact(j2+m2)));
    double S = 0.0;
    for (int v = 0; v <= j1 + j2 + j3; ++v) {
        int b1 = j3-j1+j2-v, b2 = j3+m3-v, b3 = v+j1-j2-m3, b4 = j2+j3+m1-v, b5 = j1-m1+v;
        if (b1 < 0 || b2 < 0 || b3 < 0 || b4 < 0 || b5 < 0) continue;
        double term = fact(b4)*fact(b5)/(fact(v)*fact(b1)*fact(b2)*fact(b3));
        S += ((v + j2 + m2) & 1) ? -term : term;
    }
    return pre * S;
}

struct CD { double re, im; };
constexpr CD cmul(CD a, CD b) { return { a.re*b.re - a.im*b.im, a.re*b.im + a.im*b.re }; }

constexpr CD qent(int l, int r, int c) {
    const double s = 0.70710678118654752440;
    CD v{0.0, 0.0};
    int m = r - l;
    if (m < 0)       { if (c == l - m) v = { s, 0.0 }; else if (c == l + m) v = { 0.0, -s }; }
    else if (m == 0) { if (c == l)     v = { 1.0, 0.0 }; }
    else             { double sg = (m & 1) ? -1.0 : 1.0;
                       if (c == l + m) v = { sg*s, 0.0 }; else if (c == l - m) v = { 0.0, sg*s }; }
    if      (l == 1) v = { v.im, -v.re };
    else if (l == 2) v = { -v.re, -v.im };
    return v;
}

constexpr int PA_[11] = {0,0,0,1,1,1,1,2,2,2,2};
constexpr int PB_[11] = {0,1,2,0,1,1,2,0,1,2,2};
constexpr int PC_[11] = {0,1,2,1,0,2,1,2,1,0,2};
constexpr double FAN_[3] = {3.0, 4.0, 4.0};

struct KTab { float v[9][9][9]; };

constexpr KTab buildK() {
    KTab T{};
    for (int p = 0; p < 11; ++p) {
        const int a = PA_[p], b = PB_[p], c = PC_[p];
        double cgt[5][5] = {};
        for (int i = 0; i < 2*a+1; ++i)
            for (int k = 0; k < 2*b+1; ++k) {
                int m3 = (i-a) + (k-b);
                cgt[i][k] = (m3 >= -c && m3 <= c) ? su2cg(a,b,c,i-a,k-b,m3) : 0.0;
            }
        double R[5][5][5] = {};
        double nrm = 0.0;
        for (int j = 0; j < 2*a+1; ++j)
            for (int l = 0; l < 2*b+1; ++l)
                for (int m = 0; m < 2*c+1; ++m) {
                    double re = 0.0;
                    for (int i = 0; i < 2*a+1; ++i)
                        for (int k = 0; k < 2*b+1; ++k) {
                            double g = cgt[i][k];
                            if (g == 0.0) continue;
                            int n = (i-a) + (k-b) + c;
                            CD t12 = cmul(qent(a,i,j), qent(b,k,l));
                            CD q3  = qent(c,n,m);
                            re += (t12.re*q3.re + t12.im*q3.im) * g;
                        }
                    R[j][l][m] = re;
                    nrm += re*re;
                }
        double sc = csqrt((2.0*c+1.0)/FAN_[c]) / csqrt(nrm);
        for (int j = 0; j < 2*a+1; ++j)
            for (int l = 0; l < 2*b+1; ++l)
                for (int m = 0; m < 2*c+1; ++m)
                    T.v[a*a+j][b*b+l][c*c+m] = (float)(R[j][l][m] * sc);
    }
    return T;
}

constexpr KTab KT = buildK();

constexpr bool pairNZ(int p, int di, int dj) {
    const int a = PA_[p], b = PB_[p], c = PC_[p];
    for (int dk = 0; dk < 2 * c + 1; ++dk)
        if (KT.v[a*a+di][b*b+dj][c*c+dk] != 0.0f) return true;
    return false;
}

} // namespace cg

// ===========================================================================
// Round 19: R18 (421us, VGPR 108 natural, 4 waves/SIMD) with ONE change:
// amdgpu_num_vgpr(80) -> floor(512/80) = 6 waves/SIMD (+50% latency hiding)
// under the fine-granularity allocation model (supported by R5 84->35% vs
// R16 128->20.5%). W-rows are rematerializable from LDS (broadcast reads,
// nearly free) so the squeeze should re-read rather than spill.
// ===========================================================================

#define BLK 256
#define TPV 2

typedef float f4 __attribute__((ext_vector_type(4)));
typedef float f2 __attribute__((ext_vector_type(2)));

__global__ __launch_bounds__(BLK)
__attribute__((amdgpu_num_vgpr(80)))
void tp_main_kernel(
        const float* __restrict__ x, const float* __restrict__ y,
        float* __restrict__ out, const float* __restrict__ tpw,
        const float* __restrict__ Wfx, const float* __restrict__ bfx,
        const float* __restrict__ Wfy, const float* __restrict__ bfy)
{
    __shared__ __align__(16) float Wx[9][12];   // rows padded to 12 (f4-aligned)
    __shared__ __align__(16) float Wy[9][12];
    __shared__ float bs[9];

    const int t = threadIdx.x;

    if (t < 81) { Wx[t / 9][t % 9] = Wfx[t]; Wy[t / 9][t % 9] = Wfy[t]; }
    if (t < 9)  bs[t] = bfx[t] + bfy[t];

    float w[11];
    #pragma unroll
    for (int p = 0; p < 11; ++p) {
        union { float f; int i; } u;
        u.f = tpw[p];
        u.i = __builtin_amdgcn_readfirstlane(u.i);
        w[p] = u.f;
    }

    __syncthreads();

    const long set = (long)blockIdx.x * BLK + t;   // pair index; grid exact

    // 72B slab per pair: 4 x f4 + 1 x f2 (16B-granular VMEM, 4.5 instrs)
    const float* xb = x + set * 18;
    const float* yb = y + set * 18;

    float xs[18], ys[18];   // [v*9 + comp], v in {0,1}
    #pragma unroll
    for (int q = 0; q < 4; ++q) {
        f4 a = *reinterpret_cast<const f4*>(xb + q * 4);
        xs[q*4+0] = a[0]; xs[q*4+1] = a[1]; xs[q*4+2] = a[2]; xs[q*4+3] = a[3];
        f4 b = *reinterpret_cast<const f4*>(yb + q * 4);
        ys[q*4+0] = b[0]; ys[q*4+1] = b[1]; ys[q*4+2] = b[2]; ys[q*4+3] = b[3];
    }
    {
        f2 a = *reinterpret_cast<const f2*>(xb + 16);
        xs[16] = a[0]; xs[17] = a[1];
        f2 b = *reinterpret_cast<const f2*>(yb + 16);
        ys[16] = b[0]; ys[17] = b[1];
    }

    // ---- biases ----
    float acc[18];
    #pragma unroll
    for (int k = 0; k < 9; ++k) {
        float bb = bs[k];
        acc[k] = bb; acc[9 + k] = bb;
    }

    // ---- linear branches (b128 row reads, one row live at a time) ----
    #pragma unroll
    for (int k = 0; k < 9; ++k) {
        f4 wxa = *reinterpret_cast<const f4*>(&Wx[k][0]);
        f4 wxb = *reinterpret_cast<const f4*>(&Wx[k][4]);
        float wx8 = Wx[k][8];
        f4 wya = *reinterpret_cast<const f4*>(&Wy[k][0]);
        f4 wyb = *reinterpret_cast<const f4*>(&Wy[k][4]);
        float wy8 = Wy[k][8];
        #pragma unroll
        for (int v = 0; v < TPV; ++v) {
            float s = acc[v * 9 + k];
            #pragma unroll
            for (int i = 0; i < 4; ++i) {
                s += wxa[i] * xs[v * 9 + i]     + wya[i] * ys[v * 9 + i];
                s += wxb[i] * xs[v * 9 + 4 + i] + wyb[i] * ys[v * 9 + 4 + i];
            }
            s += wx8 * xs[v * 9 + 8] + wy8 * ys[v * 9 + 8];
            acc[v * 9 + k] = s;
        }
    }

    // ---- tensor product: path-sequential, w pre-folded, acc-direct ----
    #pragma unroll
    for (int p = 0; p < 11; ++p) {
        const int a = cg::PA_[p], b = cg::PB_[p], c = cg::PC_[p];
        #pragma unroll
        for (int di = 0; di < 2 * a + 1; ++di) {
            #pragma unroll
            for (int dj = 0; dj < 2 * b + 1; ++dj) {
                if (cg::pairNZ(p, di, dj)) {
                    const int i = a * a + di, j = b * b + dj;
                    float prw[TPV];
                    #pragma unroll
                    for (int v = 0; v < TPV; ++v)
                        prw[v] = (xs[v * 9 + i] * ys[v * 9 + j]) * w[p];
                    #pragma unroll
                    for (int dk = 0; dk < 2 * c + 1; ++dk) {
                        const float kv = cg::KT.v[i][j][c * c + dk];
                        if (kv != 0.0f) {
                            #pragma unroll
                            for (int v = 0; v < TPV; ++v)
                                acc[v * 9 + c * c + dk] += kv * prw[v];
                        }
                    }
                }
            }
        }
    }

    // ---- 72B slab store: 4 x f4 + 1 x f2 ----
    float* ob = out + set * 18;
    #pragma unroll
    for (int q = 0; q < 4; ++q) {
        f4 o;
        o[0] = acc[q*4+0]; o[1] = acc[q*4+1]; o[2] = acc[q*4+2]; o[3] = acc[q*4+3];
        *reinterpret_cast<f4*>(ob + q * 4) = o;
    }
    {
        f2 o;
        o[0] = acc[16]; o[1] = acc[17];
        *reinterpret_cast<f2*>(ob + 16) = o;
    }
}

// ===========================================================================

extern "C" void kernel_launch(void* const* d_in, const int* in_sizes, int n_in,
                              void* d_out, int out_size, void* d_ws, size_t ws_size,
                              hipStream_t stream) {
    const float* x   = (const float*)d_in[0];
    const float* y   = (const float*)d_in[1];
    const float* tpw = (const float*)d_in[2];
    const float* Wfx = (const float*)d_in[3];
    const float* bfx = (const float*)d_in[4];
    const float* Wfy = (const float*)d_in[5];
    const float* bfy = (const float*)d_in[6];
    float* out = (float*)d_out;

    long n_items = (long)out_size / 9;              // 16,777,216
    long n_sets = n_items / TPV;                    // 8,388,608 pairs
    long grid = n_sets / BLK;                       // 32,768 (exact)

    hipLaunchKernelGGL(tp_main_kernel, dim3((unsigned)grid), dim3(BLK), 0, stream,
                       x, y, out, tpw, Wfx, bfx, Wfy, bfy);
}

// Round 20
// 415.506 us; speedup vs baseline: 2.1951x; 2.1951x over previous
//
#include <hip/hip_runtime.h>

// ===========================================================================
// Compile-time construction of the e3nn real Wigner-3j path tensor.
// (numerically validated rounds 3-19: absmax 0.031 vs threshold 0.259)
// ===========================================================================
namespace cg {

constexpr double csqrt(double x) {
    double g = x < 1.0 ? 1.0 : x;
    for (int i = 0; i < 64; ++i) g = 0.5 * (g + x / g);
    return g;
}
constexpr double fact(int n) { double r = 1.0; for (int i = 2; i <= n; ++i) r *= (double)i; return r; }

constexpr double su2cg(int j1, int j2, int j3, int m1, int m2, int m3) {
    if (m1 + m2 != m3) return 0.0;
    double pre = csqrt((2.0*j3+1.0)*fact(j3+j1-j2)*fact(j3-j1+j2)*fact(j1+j2-j3)
                       *fact(j3+m3)*fact(j3-m3)
                       /(fact(j1+j2+j3+1)*fact(j1-m1)*fact(j1+m1)*fact(j2-m2)*fact(j2+m2)));
    double S = 0.0;
    for (int v = 0; v <= j1 + j2 + j3; ++v) {
        int b1 = j3-j1+j2-v, b2 = j3+m3-v, b3 = v+j1-j2-m3, b4 = j2+j3+m1-v, b5 = j1-m1+v;
        if (b1 < 0 || b2 < 0 || b3 < 0 || b4 < 0 || b5 < 0) continue;
        double term = fact(b4)*fact(b5)/(fact(v)*fact(b1)*fact(b2)*fact(b3));
        S += ((v + j2 + m2) & 1) ? -term : term;
    }
    return pre * S;
}

struct CD { double re, im; };
constexpr CD cmul(CD a, CD b) { return { a.re*b.re - a.im*b.im, a.re*b.im + a.im*b.re }; }

constexpr CD qent(int l, int r, int c) {
    const double s = 0.70710678118654752440;
    CD v{0.0, 0.0};
    int m = r - l;
    if (m < 0)       { if (c == l - m) v = { s, 0.0 }; else if (c == l + m) v = { 0.0, -s }; }
    else if (m == 0) { if (c == l)     v = { 1.0, 0.0 }; }
    else             { double sg = (m & 1) ? -1.0 : 1.0;
                       if (c == l + m) v = { sg*s, 0.0 }; else if (c == l - m) v = { 0.0, sg*s }; }
    if      (l == 1) v = { v.im, -v.re };
    else if (l == 2) v = { -v.re, -v.im };
    return v;
}

constexpr int PA_[11] = {0,0,0,1,1,1,1,2,2,2,2};
constexpr int PB_[11] = {0,1,2,0,1,1,2,0,1,2,2};
constexpr int PC_[11] = {0,1,2,1,0,2,1,2,1,0,2};
constexpr double FAN_[3] = {3.0, 4.0, 4.0};

struct KTab { float v[9][9][9]; };

constexpr KTab buildK() {
    KTab T{};
    for (int p = 0; p < 11; ++p) {
        const int a = PA_[p], b = PB_[p], c = PC_[p];
        double cgt[5][5] = {};
        for (int i = 0; i < 2*a+1; ++i)
            for (int k = 0; k < 2*b+1; ++k) {
                int m3 = (i-a) + (k-b);
                cgt[i][k] = (m3 >= -c && m3 <= c) ? su2cg(a,b,c,i-a,k-b,m3) : 0.0;
            }
        double R[5][5][5] = {};
        double nrm = 0.0;
        for (int j = 0; j < 2*a+1; ++j)
            for (int l = 0; l < 2*b+1; ++l)
                for (int m = 0; m < 2*c+1; ++m) {
                    double re = 0.0;
                    for (int i = 0; i < 2*a+1; ++i)
                        for (int k = 0; k < 2*b+1; ++k) {
                            double g = cgt[i][k];
                            if (g == 0.0) continue;
                            int n = (i-a) + (k-b) + c;
                            CD t12 = cmul(qent(a,i,j), qent(b,k,l));
                            CD q3  = qent(c,n,m);
                            re += (t12.re*q3.re + t12.im*q3.im) * g;
                        }
                    R[j][l][m] = re;
                    nrm += re*re;
                }
        double sc = csqrt((2.0*c+1.0)/FAN_[c]) / csqrt(nrm);
        for (int j = 0; j < 2*a+1; ++j)
            for (int l = 0; l < 2*b+1; ++l)
                for (int m = 0; m < 2*c+1; ++m)
                    T.v[a*a+j][b*b+l][c*c+m] = (float)(R[j][l][m] * sc);
    }
    return T;
}

constexpr KTab KT = buildK();

constexpr bool pairNZ(int p, int di, int dj) {
    const int a = PA_[p], b = PB_[p], c = PC_[p];
    for (int dk = 0; dk < 2 * c + 1; ++dk)
        if (KT.v[a*a+di][b*b+dj][c*c+dk] != 0.0f) return true;
    return false;
}

} // namespace cg

// ===========================================================================
// Round 20: R18 (421us, VGPR 108 natural) with ONE change: amdgpu_num_vgpr(96)
// -> floor(512/96) = 5 waves/SIMD (+25% latency hiding vs 4). Squeeze depth
// is only 12 regs (vs R19's 28, which spilled). Last point on the occupancy
// curve: 80->spill, 96->?, 108->4w clean, 128->4w clean.
// ===========================================================================

#define BLK 256
#define TPV 2

typedef float f4 __attribute__((ext_vector_type(4)));
typedef float f2 __attribute__((ext_vector_type(2)));

__global__ __launch_bounds__(BLK)
__attribute__((amdgpu_num_vgpr(96)))
void tp_main_kernel(
        const float* __restrict__ x, const float* __restrict__ y,
        float* __restrict__ out, const float* __restrict__ tpw,
        const float* __restrict__ Wfx, const float* __restrict__ bfx,
        const float* __restrict__ Wfy, const float* __restrict__ bfy)
{
    __shared__ __align__(16) float Wx[9][12];   // rows padded to 12 (f4-aligned)
    __shared__ __align__(16) float Wy[9][12];
    __shared__ float bs[9];

    const int t = threadIdx.x;

    if (t < 81) { Wx[t / 9][t % 9] = Wfx[t]; Wy[t / 9][t % 9] = Wfy[t]; }
    if (t < 9)  bs[t] = bfx[t] + bfy[t];

    float w[11];
    #pragma unroll
    for (int p = 0; p < 11; ++p) {
        union { float f; int i; } u;
        u.f = tpw[p];
        u.i = __builtin_amdgcn_readfirstlane(u.i);
        w[p] = u.f;
    }

    __syncthreads();

    const long set = (long)blockIdx.x * BLK + t;   // pair index; grid exact

    // 72B slab per pair: 4 x f4 + 1 x f2 (16B-granular VMEM, 4.5 instrs)
    const float* xb = x + set * 18;
    const float* yb = y + set * 18;

    float xs[18], ys[18];   // [v*9 + comp], v in {0,1}
    #pragma unroll
    for (int q = 0; q < 4; ++q) {
        f4 a = *reinterpret_cast<const f4*>(xb + q * 4);
        xs[q*4+0] = a[0]; xs[q*4+1] = a[1]; xs[q*4+2] = a[2]; xs[q*4+3] = a[3];
        f4 b = *reinterpret_cast<const f4*>(yb + q * 4);
        ys[q*4+0] = b[0]; ys[q*4+1] = b[1]; ys[q*4+2] = b[2]; ys[q*4+3] = b[3];
    }
    {
        f2 a = *reinterpret_cast<const f2*>(xb + 16);
        xs[16] = a[0]; xs[17] = a[1];
        f2 b = *reinterpret_cast<const f2*>(yb + 16);
        ys[16] = b[0]; ys[17] = b[1];
    }

    // ---- biases ----
    float acc[18];
    #pragma unroll
    for (int k = 0; k < 9; ++k) {
        float bb = bs[k];
        acc[k] = bb; acc[9 + k] = bb;
    }

    // ---- linear branches (b128 row reads, one row live at a time) ----
    #pragma unroll
    for (int k = 0; k < 9; ++k) {
        f4 wxa = *reinterpret_cast<const f4*>(&Wx[k][0]);
        f4 wxb = *reinterpret_cast<const f4*>(&Wx[k][4]);
        float wx8 = Wx[k][8];
        f4 wya = *reinterpret_cast<const f4*>(&Wy[k][0]);
        f4 wyb = *reinterpret_cast<const f4*>(&Wy[k][4]);
        float wy8 = Wy[k][8];
        #pragma unroll
        for (int v = 0; v < TPV; ++v) {
            float s = acc[v * 9 + k];
            #pragma unroll
            for (int i = 0; i < 4; ++i) {
                s += wxa[i] * xs[v * 9 + i]     + wya[i] * ys[v * 9 + i];
                s += wxb[i] * xs[v * 9 + 4 + i] + wyb[i] * ys[v * 9 + 4 + i];
            }
            s += wx8 * xs[v * 9 + 8] + wy8 * ys[v * 9 + 8];
            acc[v * 9 + k] = s;
        }
    }

    // ---- tensor product: path-sequential, w pre-folded, acc-direct ----
    #pragma unroll
    for (int p = 0; p < 11; ++p) {
        const int a = cg::PA_[p], b = cg::PB_[p], c = cg::PC_[p];
        #pragma unroll
        for (int di = 0; di < 2 * a + 1; ++di) {
            #pragma unroll
            for (int dj = 0; dj < 2 * b + 1; ++dj) {
                if (cg::pairNZ(p, di, dj)) {
                    const int i = a * a + di, j = b * b + dj;
                    float prw[TPV];
                    #pragma unroll
                    for (int v = 0; v < TPV; ++v)
                        prw[v] = (xs[v * 9 + i] * ys[v * 9 + j]) * w[p];
                    #pragma unroll
                    for (int dk = 0; dk < 2 * c + 1; ++dk) {
                        const float kv = cg::KT.v[i][j][c * c + dk];
                        if (kv != 0.0f) {
                            #pragma unroll
                            for (int v = 0; v < TPV; ++v)
                                acc[v * 9 + c * c + dk] += kv * prw[v];
                        }
                    }
                }
            }
        }
    }

    // ---- 72B slab store: 4 x f4 + 1 x f2 ----
    float* ob = out + set * 18;
    #pragma unroll
    for (int q = 0; q < 4; ++q) {
        f4 o;
        o[0] = acc[q*4+0]; o[1] = acc[q*4+1]; o[2] = acc[q*4+2]; o[3] = acc[q*4+3];
        *reinterpret_cast<f4*>(ob + q * 4) = o;
    }
    {
        f2 o;
        o[0] = acc[16]; o[1] = acc[17];
        *reinterpret_cast<f2*>(ob + 16) = o;
    }
}

// ===========================================================================

extern "C" void kernel_launch(void* const* d_in, const int* in_sizes, int n_in,
                              void* d_out, int out_size, void* d_ws, size_t ws_size,
                              hipStream_t stream) {
    const float* x   = (const float*)d_in[0];
    const float* y   = (const float*)d_in[1];
    const float* tpw = (const float*)d_in[2];
    const float* Wfx = (const float*)d_in[3];
    const float* bfx = (const float*)d_in[4];
    const float* Wfy = (const float*)d_in[5];
    const float* bfy = (const float*)d_in[6];
    float* out = (float*)d_out;

    long n_items = (long)out_size / 9;              // 16,777,216
    long n_sets = n_items / TPV;                    // 8,388,608 pairs
    long grid = n_sets / BLK;                       // 32,768 (exact)

    hipLaunchKernelGGL(tp_main_kernel, dim3((unsigned)grid), dim3(BLK), 0, stream,
                       x, y, out, tpw, Wfx, bfx, Wfy, bfy);
}